// Round 1
// baseline (200.070 us; speedup 1.0000x reference)
//
#include <hip/hip_runtime.h>

typedef unsigned short u16;
typedef unsigned int u32;
typedef __bf16 bf16x8 __attribute__((ext_vector_type(8)));
typedef float f32x4 __attribute__((ext_vector_type(4)));
typedef u16 u16x4 __attribute__((ext_vector_type(4)));

#define GL2LDS16(g, l)                                                         \
    __builtin_amdgcn_global_load_lds(                                          \
        (__attribute__((address_space(1))) const void*)(g),                    \
        (__attribute__((address_space(3))) void*)(l), 16, 0, 0)

#define SYNC_VM(n) asm volatile("s_waitcnt vmcnt(" #n ")\ns_barrier" ::: "memory")
#define BAR()      asm volatile("s_barrier" ::: "memory")

// ---------- helpers ----------
__device__ __forceinline__ u16 f2bf(float f) {
    union { float f; u32 u; } x; x.f = f;
    u32 r = x.u + 0x7FFFu + ((x.u >> 16) & 1u);   // RNE (no NaNs here)
    return (u16)(r >> 16);
}

// pack 2 floats -> 2 bf16 in one u32 (round-half-up; lo=f0, hi=f1)
__device__ __forceinline__ u32 pack2bf(float f0, float f1) {
    union { float f; u32 u; } a, b;
    a.f = f0; b.f = f1;
    return __builtin_amdgcn_perm(b.u + 0x8000u, a.u + 0x8000u, 0x07060302u);
}

// fold softmax scale * log2(e) into Q fragments (scores then used with exp2)
__device__ __forceinline__ bf16x8 scale_frag(bf16x8 v) {
#pragma unroll
    for (int i = 0; i < 8; ++i) v[i] = (__bf16)((float)v[i] * 0.1803368801f);
    return v;
}

// ---------- fused fp32 -> bf16 convert (x | qkv | wo -> contiguous ws) ----------
__global__ __launch_bounds__(256) void convert_all_kernel(const float* __restrict__ x,
                                                          const float* __restrict__ qkv,
                                                          const float* __restrict__ wo,
                                                          u16* __restrict__ out) {
    int i = (blockIdx.x * 256 + threadIdx.x) * 4;
    const float* src;
    int off;
    if (i < 4194304)      { src = x;   off = i; }
    else if (i < 7340032) { src = qkv; off = i - 4194304; }
    else                  { src = wo;  off = i - 7340032; }
    float4 v = *(const float4*)(src + off);
    u16x4 o;
    o.x = f2bf(v.x); o.y = f2bf(v.y); o.z = f2bf(v.z); o.w = f2bf(v.w);
    *(u16x4*)(out + i) = o;
}

// ---------- GEMM: C[M,N] = A[M,K] * B[N,K]^T, bf16, double-buffered pipeline ----------
// FUSE_VT: blocks with n0 >= 2048 (V columns of the QKV projection) write ONLY
// the transposed copy VtG[(b*16+h)*64+dh][s] (QKVo V-cols left unwritten).
template <int TM, bool OUT_BF16, bool FUSE_VT>
__global__ __launch_bounds__(256) void gemm_bt(const u16* __restrict__ A,
                                               const u16* __restrict__ B,
                                               void* __restrict__ Cout,
                                               u16* __restrict__ VtG,
                                               int M, int N, int K) {
    constexpr int MI = TM / 32;
    __shared__ u16 As[2][TM * 32];
    __shared__ u16 Bs[2][128 * 32];
    const int tid = threadIdx.x;
    const int w = tid >> 6, lane = tid & 63, ln = lane & 15, qd = lane >> 4;
    const int wr = w >> 1, wc = w & 1;
    const int m0 = blockIdx.y * TM, n0 = blockIdx.x * 128;

    const int srow = tid >> 2, scol = (tid & 3) * 8;
    const u16* Abase = A + (size_t)(m0 + srow) * K + scol;
    const u16* Bbase = B + (size_t)(n0 + srow) * K + scol;

    f32x4 acc[MI][4] = {};
    const int nsteps = K >> 5;

#pragma unroll
    for (int it = 0; it < TM / 64; ++it)
        GL2LDS16(Abase + (size_t)(it * 64) * K, &As[0][(tid + it * 256) * 8]);
#pragma unroll
    for (int it = 0; it < 2; ++it)
        GL2LDS16(Bbase + (size_t)(it * 64) * K, &Bs[0][(tid + it * 256) * 8]);

    for (int s = 0; s < nsteps; ++s) {
        const u16* Ab = As[s & 1];
        const u16* Bb = Bs[s & 1];
        if (s + 1 < nsteps) {
            const int nk = (s + 1) << 5;
            const int nb = (s + 1) & 1;
#pragma unroll
            for (int it = 0; it < TM / 64; ++it)
                GL2LDS16(Abase + (size_t)(it * 64) * K + nk, &As[nb][(tid + it * 256) * 8]);
#pragma unroll
            for (int it = 0; it < 2; ++it)
                GL2LDS16(Bbase + (size_t)(it * 64) * K + nk, &Bs[nb][(tid + it * 256) * 8]);
            if constexpr (TM == 128) SYNC_VM(4); else SYNC_VM(3);
        } else {
            SYNC_VM(0);
        }

        bf16x8 af[MI], bfr[4];
#pragma unroll
        for (int i = 0; i < MI; ++i)
            af[i] = *(const bf16x8*)&Ab[(wr * (TM / 2) + i * 16 + ln) * 32 + qd * 8];
#pragma unroll
        for (int j = 0; j < 4; ++j)
            bfr[j] = *(const bf16x8*)&Bb[(wc * 64 + j * 16 + ln) * 32 + qd * 8];
#pragma unroll
        for (int i = 0; i < MI; ++i)
#pragma unroll
            for (int j = 0; j < 4; ++j)
                acc[i][j] = __builtin_amdgcn_mfma_f32_16x16x32_bf16(af[i], bfr[j], acc[i][j], 0, 0, 0);
        BAR();
    }

    if (FUSE_VT && n0 >= 2048) {
        // transposed V store: VtG[(b*16+h)*64 + dh][s]
        const int bq = m0 >> 11;
        const int sl = (m0 & 2047) + wr * (TM / 2) + qd * 4;
#pragma unroll
        for (int i = 0; i < MI; ++i)
#pragma unroll
            for (int j = 0; j < 4; ++j) {
                int d = n0 - 2048 + wc * 64 + j * 16 + ln;
                int vrow = (bq * 16 + (d >> 6)) * 64 + (d & 63);
                u16x4 ov;
                ov.x = f2bf(acc[i][j][0]); ov.y = f2bf(acc[i][j][1]);
                ov.z = f2bf(acc[i][j][2]); ov.w = f2bf(acc[i][j][3]);
                *(u16x4*)&VtG[(size_t)vrow * 2048 + sl + i * 16] = ov;
            }
        return;
    }

#pragma unroll
    for (int i = 0; i < MI; ++i)
#pragma unroll
        for (int j = 0; j < 4; ++j)
#pragma unroll
            for (int r = 0; r < 4; ++r) {
                int row = m0 + wr * (TM / 2) + i * 16 + qd * 4 + r;
                int col = n0 + wc * 64 + j * 16 + ln;
                float v = acc[i][j][r];
                if constexpr (OUT_BF16)
                    ((u16*)Cout)[(size_t)row * N + col] = f2bf(v);
                else
                    ((float*)Cout)[(size_t)row * N + col] = v;
            }
}

// ---------- flash attention (causal): UNPAIRED q-tiles for occupancy ----------
// One 64-q tile per block (qt = 31 - blockIdx.x, heavy tiles dispatched first).
// Grid 1024 blocks -> 4 blocks/CU (40 KiB LDS x 4 = full 160 KiB pool), double
// the previous 2 blocks/CU; staging traffic is IDENTICAL to the paired version
// (paired block staged 33 chunks for 2 tiles; unpaired pair of blocks stages
// (qtA+1)+(qtB+1) = 33 chunks total). Transposed scores (S^T = K Q^T), no-max
// exp2 softmax (scale*log2e folded into Q), GL2LDS double-buffered K/V with
// XOR-swizzled LDS, per-wave P buffer (same-wave in-order DS), in-kernel norm.
__global__ __launch_bounds__(256) void attn_kernel(const u16* __restrict__ QKV,
                                                   const u16* __restrict__ VtG,
                                                   u16* __restrict__ AO) {
    __shared__ u16 Ks[2][64 * 64];     // [key][dh], swizzled
    __shared__ u16 Vts[2][64 * 64];    // [dh][key], swizzled
    __shared__ u16 Pls[4][16 * 64];    // per wave P[q][key], swizzled

    const int tid = threadIdx.x;
    const int w = tid >> 6, lane = tid & 63, ln = lane & 15, qd = lane >> 4;
    const int b = blockIdx.z, h = blockIdx.y;
    const int qt = 31 - blockIdx.x;    // heavy (32-chunk) tiles first
    const int X = qt * 64 + w * 16;
    const int myq = X + ln;
    const int bh = b * 16 + h;
    const int swz = ln & 7;
    const int nch = qt + 1;

    // staging: slot row = tid>>3 (0..31), swizzled source colgroup
    const int sr0 = tid >> 3;
    const int sg = (tid & 7) ^ (sr0 & 7);
    const u16* ksrc = QKV + (size_t)(b * 2048 + sr0) * 3072 + 1024 + h * 64 + sg * 8;
    const u16* vsrc = VtG + (size_t)(bh * 64 + sr0) * 2048 + sg * 8;

    GL2LDS16(ksrc, &Ks[0][tid * 8]);
    GL2LDS16(ksrc + (size_t)32 * 3072, &Ks[0][tid * 8 + 2048]);
    GL2LDS16(vsrc, &Vts[0][tid * 8]);
    GL2LDS16(vsrc + (size_t)32 * 2048, &Vts[0][tid * 8 + 2048]);

    // Q B-frags, scale*log2e folded in
    const u16* qp = QKV + (size_t)(b * 2048 + myq) * 3072 + h * 64;
    bf16x8 qf0 = scale_frag(*(const bf16x8*)(qp + qd * 8));
    bf16x8 qf1 = scale_frag(*(const bf16x8*)(qp + 32 + qd * 8));

    f32x4 o[4] = {};
    float l = 0.f;
    u16* Pw = Pls[w];

    for (int c = 0; c < nch; ++c) {
        if (c + 1 < nch) {
            const int k1 = (c + 1) * 64;
            const int nb = (c + 1) & 1;
            GL2LDS16(ksrc + (size_t)k1 * 3072, &Ks[nb][tid * 8]);
            GL2LDS16(ksrc + (size_t)(k1 + 32) * 3072, &Ks[nb][tid * 8 + 2048]);
            GL2LDS16(vsrc + k1, &Vts[nb][tid * 8]);
            GL2LDS16(vsrc + k1 + 32 * 2048, &Vts[nb][tid * 8 + 2048]);
            SYNC_VM(4);
        } else {
            SYNC_VM(0);
        }
        const u16* Kb = Ks[c & 1];
        const u16* Vb = Vts[c & 1];

        // ---- S^T = K Q^T ----
        f32x4 s[4];
#pragma unroll
        for (int kt = 0; kt < 4; ++kt) {
            const u16* kr = Kb + (kt * 16 + ln) * 64;
            bf16x8 kf0 = *(const bf16x8*)(kr + ((qd ^ swz) * 8));
            bf16x8 kf1 = *(const bf16x8*)(kr + (((qd + 4) ^ swz) * 8));
            f32x4 z = {0.f, 0.f, 0.f, 0.f};
            z = __builtin_amdgcn_mfma_f32_16x16x32_bf16(kf0, qf0, z, 0, 0, 0);
            z = __builtin_amdgcn_mfma_f32_16x16x32_bf16(kf1, qf1, z, 0, 0, 0);
            s[kt] = z;
        }

        // ---- mask (diagonal chunk only) + exp2 + pack to LDS ----
        if (c == qt) {
#pragma unroll
            for (int kt = 0; kt < 4; ++kt)
#pragma unroll
                for (int r = 0; r < 4; ++r) {
                    int key = c * 64 + kt * 16 + qd * 4 + r;
                    if (key > myq) s[kt][r] = -1e30f;
                }
        }
#pragma unroll
        for (int kt = 0; kt < 4; ++kt) {
            float p0 = exp2f(s[kt][0]), p1 = exp2f(s[kt][1]);
            float p2 = exp2f(s[kt][2]), p3 = exp2f(s[kt][3]);
            l += (p0 + p1) + (p2 + p3);
            uint2 pk = {pack2bf(p0, p1), pack2bf(p2, p3)};
            int g = kt * 2 + (qd >> 1);
            *(uint2*)&Pw[ln * 64 + ((g ^ swz) * 8) + (qd & 1) * 4] = pk;
        }
        bf16x8 pf0 = *(const bf16x8*)&Pw[ln * 64 + ((qd ^ swz) * 8)];
        bf16x8 pf1 = *(const bf16x8*)&Pw[ln * 64 + (((qd + 4) ^ swz) * 8)];

        // ---- PV ----
#pragma unroll
        for (int dt = 0; dt < 4; ++dt) {
            const u16* vr = Vb + (dt * 16 + ln) * 64;
            bf16x8 vf0 = *(const bf16x8*)(vr + ((qd ^ swz) * 8));
            bf16x8 vf1 = *(const bf16x8*)(vr + (((qd + 4) ^ swz) * 8));
            o[dt] = __builtin_amdgcn_mfma_f32_16x16x32_bf16(vf0, pf0, o[dt], 0, 0, 0);
            o[dt] = __builtin_amdgcn_mfma_f32_16x16x32_bf16(vf1, pf1, o[dt], 0, 0, 0);
        }
        BAR();
    }

    // ---- deferred l reduction, normalize, packed stores ----
    l += __shfl_xor(l, 16); l += __shfl_xor(l, 32);
    float inv = 1.0f / l;
#pragma unroll
    for (int dt = 0; dt < 4; ++dt) {
        uint2 ov = {pack2bf(o[dt][0] * inv, o[dt][1] * inv),
                    pack2bf(o[dt][2] * inv, o[dt][3] * inv)};
        *(uint2*)&AO[(size_t)(b * 2048 + myq) * 1024 + h * 64 + dt * 16 + qd * 4] = ov;
    }
}

// ---------- launch ----------
extern "C" void kernel_launch(void* const* d_in, const int* in_sizes, int n_in,
                              void* d_out, int out_size, void* d_ws, size_t ws_size,
                              hipStream_t stream) {
    const float* x   = (const float*)d_in[0];   // [2,2048,1024]
    const float* qkv = (const float*)d_in[1];   // [3072,1024]
    const float* wo  = (const float*)d_in[2];   // [1024,1024]
    float* out = (float*)d_out;                 // [2,2048,1024] fp32

    char* ws = (char*)d_ws;
    u16* xb    = (u16*)(ws + 0);            //  8 MB : x bf16 [4096,1024]
    u16* qkvb  = (u16*)(ws + 8388608);      //  6 MB : qkv bf16 [3072,1024]
    u16* wob   = (u16*)(ws + 14680064);     //  2 MB : wo bf16 [1024,1024]
    u16* QKVo  = (u16*)(ws + 16777216);     // 24 MB : QKV bf16 (V-cols unwritten)
    u16* AO    = (u16*)(ws + 41943040);     //  8 MB : attn out [4096,1024]
    u16* VtG   = (u16*)(ws + 50331648);     //  8 MB : V^T [2*16*64, 2048]

    convert_all_kernel<<<8192, 256, 0, stream>>>(x, qkv, wo, xb);

    gemm_bt<128, true, true><<<dim3(24, 32), 256, 0, stream>>>(xb, qkvb, QKVo, VtG,
                                                               4096, 3072, 1024);

    attn_kernel<<<dim3(32, 16, 2), 256, 0, stream>>>(QKVo, VtG, AO);

    gemm_bt<64, false, false><<<dim3(8, 64), 256, 0, stream>>>(AO, wob, out, nullptr,
                                                               4096, 1024, 1024);
}

// Round 2
// 181.880 us; speedup vs baseline: 1.1000x; 1.1000x over previous
//
#include <hip/hip_runtime.h>

typedef unsigned short u16;
typedef unsigned int u32;
typedef __bf16 bf16x8 __attribute__((ext_vector_type(8)));
typedef float f32x4 __attribute__((ext_vector_type(4)));
typedef u16 u16x4 __attribute__((ext_vector_type(4)));

#define GL2LDS16(g, l)                                                         \
    __builtin_amdgcn_global_load_lds(                                          \
        (__attribute__((address_space(1))) const void*)(g),                    \
        (__attribute__((address_space(3))) void*)(l), 16, 0, 0)

#define SYNC_VM(n) asm volatile("s_waitcnt vmcnt(" #n ")\ns_barrier" ::: "memory")
#define BAR()      asm volatile("s_barrier" ::: "memory")

// ---------- helpers ----------
__device__ __forceinline__ u16 f2bf(float f) {
    union { float f; u32 u; } x; x.f = f;
    u32 r = x.u + 0x7FFFu + ((x.u >> 16) & 1u);   // RNE (no NaNs here)
    return (u16)(r >> 16);
}

// pack 2 floats -> 2 bf16 in one u32 (round-half-up; lo=f0, hi=f1)
__device__ __forceinline__ u32 pack2bf(float f0, float f1) {
    union { float f; u32 u; } a, b;
    a.f = f0; b.f = f1;
    return __builtin_amdgcn_perm(b.u + 0x8000u, a.u + 0x8000u, 0x07060302u);
}

// raw v_exp_f32 (2^x): skips OCML's denormal-range fixup ops. Inputs here are
// either moderate (scores) or -1e30*scale (masked) -> 0.0, both exact.
__device__ __forceinline__ float fast_exp2(float x) {
    float r;
    asm("v_exp_f32 %0, %1" : "=v"(r) : "v"(x));
    return r;
}

// fold softmax scale * log2(e) into Q fragments (scores then used with exp2)
__device__ __forceinline__ bf16x8 scale_frag(bf16x8 v) {
#pragma unroll
    for (int i = 0; i < 8; ++i) v[i] = (__bf16)((float)v[i] * 0.1803368801f);
    return v;
}

// ---------- fused fp32 -> bf16 convert (x | qkv | wo -> contiguous ws) ----------
__global__ __launch_bounds__(256) void convert_all_kernel(const float* __restrict__ x,
                                                          const float* __restrict__ qkv,
                                                          const float* __restrict__ wo,
                                                          u16* __restrict__ out) {
    int i = (blockIdx.x * 256 + threadIdx.x) * 4;
    const float* src;
    int off;
    if (i < 4194304)      { src = x;   off = i; }
    else if (i < 7340032) { src = qkv; off = i - 4194304; }
    else                  { src = wo;  off = i - 7340032; }
    float4 v = *(const float4*)(src + off);
    u16x4 o;
    o.x = f2bf(v.x); o.y = f2bf(v.y); o.z = f2bf(v.z); o.w = f2bf(v.w);
    *(u16x4*)(out + i) = o;
}

// ---------- GEMM: C[M,N] = A[M,K] * B[N,K]^T, bf16, double-buffered pipeline ----------
// FUSE_VT: blocks with n0 >= 2048 (V columns of the QKV projection) write ONLY
// the transposed copy VtG[(b*16+h)*64+dh][s] (QKVo V-cols left unwritten).
template <int TM, bool OUT_BF16, bool FUSE_VT>
__global__ __launch_bounds__(256) void gemm_bt(const u16* __restrict__ A,
                                               const u16* __restrict__ B,
                                               void* __restrict__ Cout,
                                               u16* __restrict__ VtG,
                                               int M, int N, int K) {
    constexpr int MI = TM / 32;
    __shared__ u16 As[2][TM * 32];
    __shared__ u16 Bs[2][128 * 32];
    const int tid = threadIdx.x;
    const int w = tid >> 6, lane = tid & 63, ln = lane & 15, qd = lane >> 4;
    const int wr = w >> 1, wc = w & 1;
    const int m0 = blockIdx.y * TM, n0 = blockIdx.x * 128;

    const int srow = tid >> 2, scol = (tid & 3) * 8;
    const u16* Abase = A + (size_t)(m0 + srow) * K + scol;
    const u16* Bbase = B + (size_t)(n0 + srow) * K + scol;

    f32x4 acc[MI][4] = {};
    const int nsteps = K >> 5;

#pragma unroll
    for (int it = 0; it < TM / 64; ++it)
        GL2LDS16(Abase + (size_t)(it * 64) * K, &As[0][(tid + it * 256) * 8]);
#pragma unroll
    for (int it = 0; it < 2; ++it)
        GL2LDS16(Bbase + (size_t)(it * 64) * K, &Bs[0][(tid + it * 256) * 8]);

    for (int s = 0; s < nsteps; ++s) {
        const u16* Ab = As[s & 1];
        const u16* Bb = Bs[s & 1];
        if (s + 1 < nsteps) {
            const int nk = (s + 1) << 5;
            const int nb = (s + 1) & 1;
#pragma unroll
            for (int it = 0; it < TM / 64; ++it)
                GL2LDS16(Abase + (size_t)(it * 64) * K + nk, &As[nb][(tid + it * 256) * 8]);
#pragma unroll
            for (int it = 0; it < 2; ++it)
                GL2LDS16(Bbase + (size_t)(it * 64) * K + nk, &Bs[nb][(tid + it * 256) * 8]);
            if constexpr (TM == 128) SYNC_VM(4); else SYNC_VM(3);
        } else {
            SYNC_VM(0);
        }

        bf16x8 af[MI], bfr[4];
#pragma unroll
        for (int i = 0; i < MI; ++i)
            af[i] = *(const bf16x8*)&Ab[(wr * (TM / 2) + i * 16 + ln) * 32 + qd * 8];
#pragma unroll
        for (int j = 0; j < 4; ++j)
            bfr[j] = *(const bf16x8*)&Bb[(wc * 64 + j * 16 + ln) * 32 + qd * 8];
#pragma unroll
        for (int i = 0; i < MI; ++i)
#pragma unroll
            for (int j = 0; j < 4; ++j)
                acc[i][j] = __builtin_amdgcn_mfma_f32_16x16x32_bf16(af[i], bfr[j], acc[i][j], 0, 0, 0);
        BAR();
    }

    if (FUSE_VT && n0 >= 2048) {
        // transposed V store: VtG[(b*16+h)*64 + dh][s]
        const int bq = m0 >> 11;
        const int sl = (m0 & 2047) + wr * (TM / 2) + qd * 4;
#pragma unroll
        for (int i = 0; i < MI; ++i)
#pragma unroll
            for (int j = 0; j < 4; ++j) {
                int d = n0 - 2048 + wc * 64 + j * 16 + ln;
                int vrow = (bq * 16 + (d >> 6)) * 64 + (d & 63);
                u16x4 ov;
                ov.x = f2bf(acc[i][j][0]); ov.y = f2bf(acc[i][j][1]);
                ov.z = f2bf(acc[i][j][2]); ov.w = f2bf(acc[i][j][3]);
                *(u16x4*)&VtG[(size_t)vrow * 2048 + sl + i * 16] = ov;
            }
        return;
    }

#pragma unroll
    for (int i = 0; i < MI; ++i)
#pragma unroll
        for (int j = 0; j < 4; ++j)
#pragma unroll
            for (int r = 0; r < 4; ++r) {
                int row = m0 + wr * (TM / 2) + i * 16 + qd * 4 + r;
                int col = n0 + wc * 64 + j * 16 + ln;
                float v = acc[i][j][r];
                if constexpr (OUT_BF16)
                    ((u16*)Cout)[(size_t)row * N + col] = f2bf(v);
                else
                    ((float*)Cout)[(size_t)row * N + col] = v;
            }
}

// ---------- flash attention (causal): 32-row q-tile PAIRS ----------
// R1 lesson: all blocks are co-resident (static scheduling) -> block work MUST
// be uniform. Pair 32-row q-tiles (t, 63-t): waves 0-1 own heavy tile 63-t
// (active all nchH chunks), waves 2-3 own light tile t (active while c<nchL).
// nchH + nchL == 33 for every t -> uniform compute per block, 1024 blocks ->
// 4 blocks/CU (40KiB LDS x4 = full 160KiB pool), 16 waves/CU = 2x the paired-64
// version's parallelism. K/V staged once per block, shared by both tiles.
// Transposed scores (S^T = K Q^T), no-max exp2 softmax (scale*log2e folded
// into Q, raw v_exp_f32), GL2LDS double-buffered K/V with XOR-swizzled LDS,
// per-wave P buffer (same-wave in-order DS), in-kernel normalization.
__global__ __launch_bounds__(256) void attn_kernel(const u16* __restrict__ QKV,
                                                   const u16* __restrict__ VtG,
                                                   u16* __restrict__ AO) {
    __shared__ u16 Ks[2][64 * 64];     // [key][dh], swizzled
    __shared__ u16 Vts[2][64 * 64];    // [dh][key], swizzled
    __shared__ u16 Pls[4][16 * 64];    // per wave P[q][key], swizzled

    const int tid = threadIdx.x;
    const int w = tid >> 6, lane = tid & 63, ln = lane & 15, qd = lane >> 4;
    const int b = blockIdx.z, h = blockIdx.y;
    const int t = blockIdx.x;              // pair index 0..31 (heavy-first order)
    const int tH = 63 - t, tL = t;         // 32-row q tiles
    const int tile = (w < 2) ? tH : tL;
    const int myq = tile * 32 + (w & 1) * 16 + ln;
    const int bh = b * 16 + h;
    const int swz = ln & 7;
    const int nchH = (tH >> 1) + 1;        // 17..32
    const int mynch = (tile >> 1) + 1;     // chunks this wave is active for

    // staging: slot row = tid>>3 (0..31), swizzled source colgroup
    const int sr0 = tid >> 3;
    const int sg = (tid & 7) ^ (sr0 & 7);
    const u16* ksrc = QKV + (size_t)(b * 2048 + sr0) * 3072 + 1024 + h * 64 + sg * 8;
    const u16* vsrc = VtG + (size_t)(bh * 64 + sr0) * 2048 + sg * 8;

    GL2LDS16(ksrc, &Ks[0][tid * 8]);
    GL2LDS16(ksrc + (size_t)32 * 3072, &Ks[0][tid * 8 + 2048]);
    GL2LDS16(vsrc, &Vts[0][tid * 8]);
    GL2LDS16(vsrc + (size_t)32 * 2048, &Vts[0][tid * 8 + 2048]);

    // Q B-frags, scale*log2e folded in
    const u16* qp = QKV + (size_t)(b * 2048 + myq) * 3072 + h * 64;
    bf16x8 qf0 = scale_frag(*(const bf16x8*)(qp + qd * 8));
    bf16x8 qf1 = scale_frag(*(const bf16x8*)(qp + 32 + qd * 8));

    f32x4 o[4] = {};
    float l = 0.f;
    u16* Pw = Pls[w];

    for (int c = 0; c < nchH; ++c) {
        if (c + 1 < nchH) {
            const int k1 = (c + 1) * 64;
            const int nb = (c + 1) & 1;
            GL2LDS16(ksrc + (size_t)k1 * 3072, &Ks[nb][tid * 8]);
            GL2LDS16(ksrc + (size_t)(k1 + 32) * 3072, &Ks[nb][tid * 8 + 2048]);
            GL2LDS16(vsrc + k1, &Vts[nb][tid * 8]);
            GL2LDS16(vsrc + k1 + 32 * 2048, &Vts[nb][tid * 8 + 2048]);
            SYNC_VM(4);
        } else {
            SYNC_VM(0);
        }

        if (c < mynch) {
            const u16* Kb = Ks[c & 1];
            const u16* Vb = Vts[c & 1];

            // ---- S^T = K Q^T ----
            f32x4 s[4];
#pragma unroll
            for (int kt = 0; kt < 4; ++kt) {
                const u16* kr = Kb + (kt * 16 + ln) * 64;
                bf16x8 kf0 = *(const bf16x8*)(kr + ((qd ^ swz) * 8));
                bf16x8 kf1 = *(const bf16x8*)(kr + (((qd + 4) ^ swz) * 8));
                f32x4 z = {0.f, 0.f, 0.f, 0.f};
                z = __builtin_amdgcn_mfma_f32_16x16x32_bf16(kf0, qf0, z, 0, 0, 0);
                z = __builtin_amdgcn_mfma_f32_16x16x32_bf16(kf1, qf1, z, 0, 0, 0);
                s[kt] = z;
            }

            // ---- mask (diagonal chunk only) + exp2 + pack to LDS ----
            if (c == mynch - 1) {
#pragma unroll
                for (int kt = 0; kt < 4; ++kt)
#pragma unroll
                    for (int r = 0; r < 4; ++r) {
                        int key = c * 64 + kt * 16 + qd * 4 + r;
                        if (key > myq) s[kt][r] = -1e30f;
                    }
            }
#pragma unroll
            for (int kt = 0; kt < 4; ++kt) {
                float p0 = fast_exp2(s[kt][0]), p1 = fast_exp2(s[kt][1]);
                float p2 = fast_exp2(s[kt][2]), p3 = fast_exp2(s[kt][3]);
                l += (p0 + p1) + (p2 + p3);
                uint2 pk = {pack2bf(p0, p1), pack2bf(p2, p3)};
                int g = kt * 2 + (qd >> 1);
                *(uint2*)&Pw[ln * 64 + ((g ^ swz) * 8) + (qd & 1) * 4] = pk;
            }
            bf16x8 pf0 = *(const bf16x8*)&Pw[ln * 64 + ((qd ^ swz) * 8)];
            bf16x8 pf1 = *(const bf16x8*)&Pw[ln * 64 + (((qd + 4) ^ swz) * 8)];

            // ---- PV ----
#pragma unroll
            for (int dt = 0; dt < 4; ++dt) {
                const u16* vr = Vb + (dt * 16 + ln) * 64;
                bf16x8 vf0 = *(const bf16x8*)(vr + ((qd ^ swz) * 8));
                bf16x8 vf1 = *(const bf16x8*)(vr + (((qd + 4) ^ swz) * 8));
                o[dt] = __builtin_amdgcn_mfma_f32_16x16x32_bf16(vf0, pf0, o[dt], 0, 0, 0);
                o[dt] = __builtin_amdgcn_mfma_f32_16x16x32_bf16(vf1, pf1, o[dt], 0, 0, 0);
            }
        }
        BAR();
    }

    // ---- deferred l reduction, normalize, packed stores ----
    l += __shfl_xor(l, 16); l += __shfl_xor(l, 32);
    float inv = 1.0f / l;
#pragma unroll
    for (int dt = 0; dt < 4; ++dt) {
        uint2 ov = {pack2bf(o[dt][0] * inv, o[dt][1] * inv),
                    pack2bf(o[dt][2] * inv, o[dt][3] * inv)};
        *(uint2*)&AO[(size_t)(b * 2048 + myq) * 1024 + h * 64 + dt * 16 + qd * 4] = ov;
    }
}

// ---------- launch ----------
extern "C" void kernel_launch(void* const* d_in, const int* in_sizes, int n_in,
                              void* d_out, int out_size, void* d_ws, size_t ws_size,
                              hipStream_t stream) {
    const float* x   = (const float*)d_in[0];   // [2,2048,1024]
    const float* qkv = (const float*)d_in[1];   // [3072,1024]
    const float* wo  = (const float*)d_in[2];   // [1024,1024]
    float* out = (float*)d_out;                 // [2,2048,1024] fp32

    char* ws = (char*)d_ws;
    u16* xb    = (u16*)(ws + 0);            //  8 MB : x bf16 [4096,1024]
    u16* qkvb  = (u16*)(ws + 8388608);      //  6 MB : qkv bf16 [3072,1024]
    u16* wob   = (u16*)(ws + 14680064);     //  2 MB : wo bf16 [1024,1024]
    u16* QKVo  = (u16*)(ws + 16777216);     // 24 MB : QKV bf16 (V-cols unwritten)
    u16* AO    = (u16*)(ws + 41943040);     //  8 MB : attn out [4096,1024]
    u16* VtG   = (u16*)(ws + 50331648);     //  8 MB : V^T [2*16*64, 2048]

    convert_all_kernel<<<8192, 256, 0, stream>>>(x, qkv, wo, xb);

    gemm_bt<128, true, true><<<dim3(24, 32), 256, 0, stream>>>(xb, qkvb, QKVo, VtG,
                                                               4096, 3072, 1024);

    attn_kernel<<<dim3(32, 16, 2), 256, 0, stream>>>(QKVo, VtG, AO);

    gemm_bt<64, false, false><<<dim3(8, 64), 256, 0, stream>>>(AO, wob, out, nullptr,
                                                               4096, 1024, 1024);
}